// Round 5
// baseline (442.182 us; speedup 1.0000x reference)
//
#include <hip/hip_runtime.h>
#include <hip/hip_bf16.h>

typedef short bf16x4 __attribute__((ext_vector_type(4)));
typedef short bf16x8 __attribute__((ext_vector_type(8)));
typedef float f32x4  __attribute__((ext_vector_type(4)));

__device__ inline unsigned short f2us(float f) {
    __hip_bfloat16 h = __float2bfloat16(f);
    return *(unsigned short*)&h;
}
__device__ inline float us2f(unsigned short u) {
    union { unsigned int i; float f; } c; c.i = ((unsigned int)u) << 16; return c.f;
}
__device__ inline float tanh_fast(float x) {
    float xs = fminf(fmaxf(x, -20.f), 20.f);
    float t = __expf(2.f * xs);
    return 1.f - 2.f / (t + 1.f);
}

// async global->LDS, 16 B per lane; LDS dest = wave-uniform base + lane*16
__device__ inline void gload_lds16(const void* g, void* l) {
    __builtin_amdgcn_global_load_lds(
        (const __attribute__((address_space(1))) void*)g,
        (__attribute__((address_space(3))) void*)l,
        16, 0, 0);
}

// ---------------- fused prep: x->bf16 CL | weights->B-frag | BN fold | zeropage -
__global__ __launch_bounds__(256)
void prep_all(const float* __restrict__ x, unsigned short* __restrict__ xcl,
              const float* __restrict__ w0, const float* __restrict__ wm,
              const float* __restrict__ wl, unsigned short* __restrict__ Wf,
              const float* b0, const float* g0, const float* be0,
              const float* m0, const float* v0,
              const float* bm, const float* gm, const float* bem,
              const float* mm, const float* vm,
              const float* bl, const float* gl, const float* bel,
              const float* ml, const float* vl,
              float* __restrict__ Af, float* __restrict__ Bf,
              unsigned int* __restrict__ zp)
{
    const int bid = blockIdx.x;
    const int t = threadIdx.x;
    if (bid < 1024) {
        __shared__ unsigned short t2[128 * 68];
        int n = bid >> 7, h = bid & 127;
        const float* xp = x + (size_t)n * 64 * 16384 + h * 128;
        for (int i = t; i < 8192; i += 256) {
            int ci = i >> 7, w = i & 127;
            t2[w * 68 + ci] = f2us(xp[(size_t)ci * 16384 + w]);
        }
        __syncthreads();
        unsigned short* op = xcl + ((size_t)(n * 16384 + h * 128)) * 64;
        for (int i = t; i < 1024; i += 256) {
            int w = i >> 3, c8 = i & 7;
            union { bf16x4 v[2]; uint4 q; } u;
            u.v[0] = *(bf16x4*)&t2[w * 68 + c8 * 8];
            u.v[1] = *(bf16x4*)&t2[w * 68 + c8 * 8 + 4];
            *(uint4*)(op + w * 64 + c8 * 8) = u.q;
        }
    } else if (bid < 2032) {
        int idx = (bid - 1024) * 256 + t;
        int l = idx / 36864, r = idx - l * 36864;
        int tp = r >> 12, r2 = r & 4095;
        int hh = r2 >> 11, nb = (r2 >> 9) & 3, ln = (r2 >> 3) & 63, j = r2 & 7;
        int ci = hh * 32 + (ln >> 4) * 8 + j;
        int co = (ln & 15) * 4 + nb;          // permuted co
        float val = 0.f;
        if (l < 6) {
            const float* src = (l == 0) ? w0 : (wm + (size_t)(l - 1) * 36864);
            val = src[(co * 64 + ci) * 9 + tp];
        } else if (co < 36) {
            val = wl[(co * 64 + ci) * 9 + tp];
        }
        Wf[idx] = f2us(val);
    } else {
        int idx = (bid - 2032) * 256 + t;
        if (bid == 2033 && t >= 192) zp[t - 192] = 0u;   // 256 B zero page
        if (idx < 448) {
            int l = idx >> 6, c = idx & 63;
            float b, g, be, m, v;
            bool zero = false;
            if (l == 0) {
                b = b0[c]; g = g0[c]; be = be0[c]; m = m0[c]; v = v0[c];
            } else if (l < 6) {
                int o = (l - 1) * 64 + c;
                b = bm[o]; g = gm[o]; be = bem[o]; m = mm[o]; v = vm[o];
            } else if (c < 36) {
                b = bl[c]; g = gl[c]; be = bel[c]; m = ml[c]; v = vl[c];
            } else zero = true;
            if (zero) { Af[idx] = 0.f; Bf[idx] = 0.f; }
            else {
                float s = g / sqrtf(v + 1e-5f);
                Af[idx] = s;
                Bf[idx] = (b - m) * s + be;
            }
        }
    }
}

// ---------------- persistent fused conv chain + dynamic conv -------------------
// 256 blocks (cooperative, 1/CU) x 512 thr. Tile 32x16 lives in LDS across all
// 7 layers; interior of next layer's input = own epilogue, written to LDS only.
// Boundary ring exchanged via agent-scope relaxed atomics (u64) through the
// coherence point + per-block magic flags. NO grid.sync / threadfence -> own
// L2/LDS state survives. Weights prefetched to VGPRs pre-MFMA, LDS'd post-barrier.
struct Mega2Args {
    const float *x, *bas, *Af, *Bf;
    const unsigned short *xcl, *Wfb, *zp;
    unsigned short *s0, *s1;            // strip parity buffers
    unsigned long long *flags;
    float *out;
};

#define LDS_W_OFF 78336
#define FLAGV(v) ((0xAB5EED00ULL << 32) | (unsigned long long)(v))

#define MFMA_BLOCK(ACC)                                                        \
    _Pragma("unroll")                                                          \
    for (int tp = 0; tp < 9; ++tp) {                                           \
        const int ky = tp / 3, kx = tp % 3;                                    \
        bf16x8 bfr[2][4];                                                      \
        _Pragma("unroll")                                                      \
        for (int hh = 0; hh < 2; ++hh)                                         \
            _Pragma("unroll")                                                  \
            for (int nb = 0; nb < 4; ++nb)                                     \
                bfr[hh][nb] = *(const bf16x8*)(smem + LDS_W_OFF +              \
                    (((((tp * 2 + hh) * 4 + nb) * 64) + ln) << 4));            \
        _Pragma("unroll")                                                      \
        for (int rh = 0; rh < 2; ++rh) {                                       \
            _Pragma("unroll")                                                  \
            for (int hf = 0; hf < 2; ++hf) {                                   \
                const int p = (rbase + rh + ky) * 34 + hf * 16 + xln + kx;     \
                const int pb = p * 128, sw = (p & 7) << 4;                     \
                _Pragma("unroll")                                              \
                for (int hh = 0; hh < 2; ++hh) {                               \
                    bf16x8 afr = *(const bf16x8*)(smem + pb +                  \
                                        (((qd + 4 * hh) << 4) ^ sw));          \
                    _Pragma("unroll")                                          \
                    for (int nb = 0; nb < 4; ++nb)                             \
                        ACC[rh][hf][nb] =                                      \
                            __builtin_amdgcn_mfma_f32_16x16x32_bf16(           \
                                afr, bfr[hh][nb], ACC[rh][hf][nb], 0, 0, 0);   \
                }                                                              \
            }                                                                  \
        }                                                                      \
    }

__global__ __launch_bounds__(512, 2) void mega2(Mega2Args g)
{
    __shared__ __align__(16) unsigned char smem[152064];
    const int bid = blockIdx.x;
    const int bx = bid & 3, by = (bid >> 2) & 7, cn = bid >> 5;
    const int h0 = by * 16, w0c = bx * 32;
    const int t = threadIdx.x;
    const int ln = t & 63, wv = t >> 6;
    const int xln = ln & 15, qd = ln >> 4;
    const int rbase = wv * 2;
    const size_t ibase = (size_t)cn * 16384 * 64;

    // ---- layer-0 staging: tile from xcl + W0 via DMA
    {
        const unsigned short* srcn = g.xcl + ibase;
        for (int i = wv; i < 77; i += 8) {
            int gg = i * 64 + ln;
            int p = gg >> 3, jj = gg & 7;
            int ty = (p * 1928) >> 16;          // p/34, exact for p<612
            int tx = p - ty * 34;
            int gy = h0 + ty - 1, gx = w0c + tx - 1;
            int js = jj ^ (p & 7);
            const unsigned short* gsrc =
                (((unsigned)gy < 128u) & ((unsigned)gx < 128u))
                    ? srcn + (ptrdiff_t)(gy * 128 + gx) * 64 + js * 8
                    : g.zp;
            if (gg < 4896) gload_lds16(gsrc, smem + (size_t)i * 1024);
        }
        for (int i = wv; i < 72; i += 8)
            gload_lds16(g.Wfb + ((size_t)(i * 64 + ln)) * 8,
                        smem + LDS_W_OFF + (size_t)i * 1024);
        __syncthreads();
    }

#pragma unroll 1
    for (int l = 0; l < 6; ++l) {
        // prefetch next layer's weights into regs (overlaps MFMA)
        uint4 wpre[9];
        {
            const uint4* wnext = (const uint4*)(g.Wfb + (size_t)(l + 1) * 36864);
#pragma unroll
            for (int k = 0; k < 9; ++k) wpre[k] = wnext[t + 512 * k];
        }

        f32x4 acc[2][2][4];
#pragma unroll
        for (int rh = 0; rh < 2; ++rh)
#pragma unroll
            for (int hf = 0; hf < 2; ++hf)
#pragma unroll
                for (int nb = 0; nb < 4; ++nb)
                    acc[rh][hf][nb] = (f32x4){0.f, 0.f, 0.f, 0.f};

        MFMA_BLOCK(acc);

        __syncthreads();   // B1: all LDS reads (tile + W) complete

        // epilogue: BN+tanh; interior -> LDS tile (+1,+1); boundary -> strips
        unsigned short* stripb = (l & 1) ? g.s1 : g.s0;
        const float4 A4 = *(const float4*)&g.Af[l * 64 + xln * 4];
        const float4 B4 = *(const float4*)&g.Bf[l * 64 + xln * 4];
        const int cchunk = xln >> 1, coff = (xln & 1) * 8;
#pragma unroll
        for (int rh = 0; rh < 2; ++rh) {
            const int oy = rbase + rh;
#pragma unroll
            for (int hf = 0; hf < 2; ++hf) {
#pragma unroll
                for (int r = 0; r < 4; ++r) {
                    const int ox = hf * 16 + qd * 4 + r;
                    union { ushort4 s; unsigned long long u; } o;
                    o.s.x = f2us(tanh_fast(fmaf(acc[rh][hf][0][r], A4.x, B4.x)));
                    o.s.y = f2us(tanh_fast(fmaf(acc[rh][hf][1][r], A4.y, B4.y)));
                    o.s.z = f2us(tanh_fast(fmaf(acc[rh][hf][2][r], A4.z, B4.z)));
                    o.s.w = f2us(tanh_fast(fmaf(acc[rh][hf][3][r], A4.w, B4.w)));
                    const int p = (oy + 1) * 34 + (ox + 1);
                    *(unsigned long long*)(smem + p * 128 +
                        (((cchunk ^ (p & 7)) << 4) | coff)) = o.u;
                    if (oy == 0 || oy == 15 || ox == 0 || ox == 31) {
                        unsigned long long* sp = (unsigned long long*)(stripb +
                            ibase + (size_t)((h0 + oy) * 128 + (w0c + ox)) * 64 +
                            xln * 4);
                        __hip_atomic_store(sp, o.u, __ATOMIC_RELAXED,
                                           __HIP_MEMORY_SCOPE_AGENT);
                    }
                }
            }
        }
        // next layer's weights into LDS (W reads finished at B1)
        {
            uint4* wdst = (uint4*)(smem + LDS_W_OFF);
#pragma unroll
            for (int k = 0; k < 9; ++k) wdst[t + 512 * k] = wpre[k];
        }
        asm volatile("s_waitcnt vmcnt(0)" ::: "memory");
        __syncthreads();   // B2: strips at coherence point, LDS writes done

        if (t == 0)
            __hip_atomic_store(&g.flags[bid], FLAGV(l + 1),
                               __ATOMIC_RELAXED, __HIP_MEMORY_SCOPE_AGENT);
        if (t < 8) {       // publish-then-wait: deadlock-free
            int tt = t + (t >= 4);
            int dx = tt % 3 - 1, dy = tt / 3 - 1;
            int nbx = bx + dx, nby = by + dy;
            if (((unsigned)nbx < 4u) & ((unsigned)nby < 8u)) {
                const unsigned long long* fp =
                    g.flags + (cn * 32 + nby * 4 + nbx);
                const unsigned long long tgt = FLAGV(l + 1);
                while (__hip_atomic_load(fp, __ATOMIC_RELAXED,
                                         __HIP_MEMORY_SCOPE_AGENT) != tgt)
                    __builtin_amdgcn_s_sleep(2);
            }
        }
        __syncthreads();   // B3: all neighbors published

        // halo ingest: ring = rows 0,17 (34 px each) + cols 0,33 (16 px each)
        for (int idx = t; idx < 1600; idx += 512) {
            int p5 = idx >> 4, j2 = idx & 15;
            int ty, tx;
            if (p5 < 34)      { ty = 0;  tx = p5; }
            else if (p5 < 68) { ty = 17; tx = p5 - 34; }
            else { int k = p5 - 68; ty = 1 + (k >> 1); tx = (k & 1) ? 33 : 0; }
            int gy = h0 + ty - 1, gx = w0c + tx - 1;
            unsigned long long v = 0ull;
            if (((unsigned)gy < 128u) & ((unsigned)gx < 128u)) {
                const unsigned long long* sp = (const unsigned long long*)(stripb +
                    ibase + (size_t)(gy * 128 + gx) * 64) + j2;
                v = __hip_atomic_load(sp, __ATOMIC_RELAXED,
                                      __HIP_MEMORY_SCOPE_AGENT);
            }
            int p = ty * 34 + tx;
            *(unsigned long long*)(smem + p * 128 +
                ((((j2 >> 1) ^ (p & 7)) << 4) | ((j2 & 1) * 8))) = v;
        }
        __syncthreads();   // B4: tile ready
    }

    // ---- layer 6: conv -> h7 in LDS, then dynamic conv (R4-verified code)
    {
        f32x4 acc[2][2][4];
#pragma unroll
        for (int rh = 0; rh < 2; ++rh)
#pragma unroll
            for (int hf = 0; hf < 2; ++hf)
#pragma unroll
                for (int nb = 0; nb < 4; ++nb)
                    acc[rh][hf][nb] = (f32x4){0.f, 0.f, 0.f, 0.f};
        MFMA_BLOCK(acc);
        __syncthreads();

        unsigned short* h7 = (unsigned short*)(smem + LDS_W_OFF);
        const float4 A4 = *(const float4*)&g.Af[6 * 64 + xln * 4];
        const float4 B4 = *(const float4*)&g.Bf[6 * 64 + xln * 4];
        const int cchunk = xln >> 1, coff = (xln & 1) * 8;
#pragma unroll
        for (int rh = 0; rh < 2; ++rh) {
#pragma unroll
            for (int hf = 0; hf < 2; ++hf) {
#pragma unroll
                for (int r = 0; r < 4; ++r) {
                    const int pl = (rbase + rh) * 32 + hf * 16 + qd * 4 + r;
                    ushort4 o;
                    o.x = f2us(tanh_fast(fmaf(acc[rh][hf][0][r], A4.x, B4.x)));
                    o.y = f2us(tanh_fast(fmaf(acc[rh][hf][1][r], A4.y, B4.y)));
                    o.z = f2us(tanh_fast(fmaf(acc[rh][hf][2][r], A4.z, B4.z)));
                    o.w = f2us(tanh_fast(fmaf(acc[rh][hf][3][r], A4.w, B4.w)));
                    *(ushort4*)((unsigned char*)h7 + pl * 128 +
                                (((cchunk ^ (pl & 7)) << 4) | coff)) = o;
                }
            }
        }
        __syncthreads();

        // dynamic conv: 1 px/thread
        const int pxx = t & 31, py = t >> 5;
        const int h = h0 + py, w = w0c + pxx;

        float bs[54];
#pragma unroll
        for (int i = 0; i < 54; ++i) bs[i] = g.bas[i];

        union { uint4 q[5]; unsigned short s[40]; } hv;
        {
            const int pl = py * 32 + pxx;
            const unsigned char* hb = smem + LDS_W_OFF + pl * 128;
#pragma unroll
            for (int j = 0; j < 5; ++j)
                hv.q[j] = *(const uint4*)(hb + ((j ^ (pl & 7)) << 4));
        }

        float coef[54];
#pragma unroll
        for (int i = 0; i < 54; ++i) coef[i] = 0.f;
#pragma unroll
        for (int m = 0; m < 6; ++m)
#pragma unroll
            for (int k = 0; k < 6; ++k) {
                float f = us2f(hv.s[m * 6 + k]);
#pragma unroll
                for (int lq = 0; lq < 9; ++lq)
                    coef[m * 9 + lq] = fmaf(f, bs[k * 9 + lq], coef[m * 9 + lq]);
            }

        const float* xp = g.x + (size_t)cn * 64 * 16384;
        float* op = g.out + (size_t)cn * 384 * 16384 + h * 128 + w;
        float* tile = (float*)smem;     // [ci][18][34] f32 = 78336 B

        for (int half = 0; half < 2; ++half) {
            __syncthreads();
            for (int idx = t; idx < 19584; idx += 512) {
                int y = ((idx >> 6) * 3856) >> 16;          // idx/1088
                int rem = idx - y * 1088;
                int ci = (rem * 1928) >> 16;                // rem/34
                int xw = rem - ci * 34;
                int gy = h0 + y - 1, gx = w0c + xw - 1;
                float v = 0.f;
                if ((unsigned)gy < 128u && (unsigned)gx < 128u)
                    v = xp[(size_t)(half * 32 + ci) * 16384 + gy * 128 + gx];
                tile[ci * 612 + y * 34 + xw] = v;
            }
            __syncthreads();

#pragma unroll 1
            for (int c = 0; c < 32; ++c) {
                float xv[9];
#pragma unroll
                for (int ky = 0; ky < 3; ++ky)
#pragma unroll
                    for (int kx = 0; kx < 3; ++kx)
                        xv[ky * 3 + kx] =
                            tile[c * 612 + (py + ky) * 34 + (pxx + kx)];
                int cgc = half * 32 + c;
#pragma unroll
                for (int m = 0; m < 6; ++m) {
                    float s = 0.f;
#pragma unroll
                    for (int lq = 0; lq < 9; ++lq)
                        s = fmaf(coef[m * 9 + lq], xv[lq], s);
                    op[(size_t)(cgc * 6 + m) * 16384] = s;
                }
            }
        }
    }
}

// ---------------- launch -------------------------------------------------------
extern "C" void kernel_launch(void* const* d_in, const int* in_sizes, int n_in,
                              void* d_out, int out_size, void* d_ws, size_t ws_size,
                              hipStream_t stream)
{
    const float* x   = (const float*)d_in[0];
    const float* w0  = (const float*)d_in[1];
    const float* b0  = (const float*)d_in[2];
    const float* g0  = (const float*)d_in[3];
    const float* be0 = (const float*)d_in[4];
    const float* m0  = (const float*)d_in[5];
    const float* v0  = (const float*)d_in[6];
    const float* wm  = (const float*)d_in[7];
    const float* bm  = (const float*)d_in[8];
    const float* gm  = (const float*)d_in[9];
    const float* bem = (const float*)d_in[10];
    const float* mm  = (const float*)d_in[11];
    const float* vm  = (const float*)d_in[12];
    const float* wl  = (const float*)d_in[13];
    const float* bl  = (const float*)d_in[14];
    const float* gl  = (const float*)d_in[15];
    const float* bel = (const float*)d_in[16];
    const float* ml  = (const float*)d_in[17];
    const float* vl  = (const float*)d_in[18];
    const float* bas = (const float*)d_in[19];

    unsigned short* Wfb = (unsigned short*)d_ws;                    // 516096 B
    float* Af  = (float*)((char*)d_ws + 524288);                    // 448 floats
    float* Bf  = Af + 448;
    unsigned int* zp = (unsigned int*)((char*)d_ws + (1 << 20));    // 256 B zeros
    unsigned long long* flags =
        (unsigned long long*)((char*)d_ws + (1 << 20) + 4096);      // 256 u64
    unsigned short* xcl  = (unsigned short*)((char*)d_ws + (size_t)(2 << 20));
    unsigned short* bufA = (unsigned short*)((char*)d_ws + (size_t)(2 << 20) + 16777216);
    unsigned short* bufB = (unsigned short*)((char*)d_ws + (size_t)(2 << 20) + 2 * 16777216);

    prep_all<<<2034, 256, 0, stream>>>(x, xcl, w0, wm, wl, Wfb,
                                       b0, g0, be0, m0, v0,
                                       bm, gm, bem, mm, vm,
                                       bl, gl, bel, ml, vl, Af, Bf, zp);

    Mega2Args a;
    a.x = x; a.bas = bas; a.Af = Af; a.Bf = Bf;
    a.xcl = xcl; a.Wfb = Wfb; a.zp = (const unsigned short*)zp;
    a.s0 = bufA; a.s1 = bufB;
    a.flags = flags;
    a.out = (float*)d_out;

    void* ka[] = {&a};
    hipLaunchCooperativeKernel((const void*)mega2, dim3(256), dim3(512), ka, 0, stream);
}